// Round 13
// baseline (212.411 us; speedup 1.0000x reference)
//
#include <hip/hip_runtime.h>
#include <hip/hip_bf16.h>
#include <math.h>

// Shapes (fixed by the reference)
#define Bdim 16
#define Ndim 1024
#define Ddim 256
#define Hdim 8
#define HDdim 32
#define INdim 256
#define HIDdim 1024
#define Tdim (Bdim * Ndim)   // 16384 rows

typedef __attribute__((ext_vector_type(8)))  short bf16x8;
typedef __attribute__((ext_vector_type(4)))  short bf16x4;
typedef __attribute__((ext_vector_type(16))) float f32x16;
typedef unsigned int u32;

__device__ inline short f2bf(float x) {
    union { __hip_bfloat16 b; short s; } u;
    u.b = __float2bfloat16(x);
    return u.s;
}

__device__ inline float bf2f(short s) {
    return __uint_as_float(((u32)(unsigned short)s) << 16);
}

// raw v_exp_f32 (scores are bounded; no libm range handling needed)
__device__ inline float fexp2(float x) {
#if __has_builtin(__builtin_amdgcn_exp2f)
    return __builtin_amdgcn_exp2f(x);
#else
    return exp2f(x);
#endif
}

// pack two f32 -> two bf16 in a u32
__device__ inline u32 pack2bf(float a, float b) {
#if __has_builtin(__builtin_amdgcn_cvt_pk_bf16_f32)
    typedef __attribute__((ext_vector_type(2))) __bf16 bf16x2_t;
    union { bf16x2_t v; u32 u; } c;
    c.v = __builtin_amdgcn_cvt_pk_bf16_f32(a, b);
    return c.u;
#else
    u32 ua = __float_as_uint(a), ub = __float_as_uint(b);
    return ((ua + 0x8000u) >> 16) | ((ub + 0x8000u) & 0xffff0000u);
#endif
}

// v_permlane32_swap_b32: after execution a = {a.lo32, b.lo32}, b = {a.hi32, b.hi32}
__device__ inline void plswap(u32 &a, u32 &b) {
    asm volatile("v_permlane32_swap_b32 %0, %1" : "+v"(a), "+v"(b));
}

__device__ inline float gelu_exact(float v) {
    return 0.5f * v * (1.0f + erff(v * 0.70710678118654752f));
}

// direct global->LDS copy, 16B per lane. LDS dest is wave-uniform base +
// lane*16 (HW-enforced); global src is per-lane.
typedef __attribute__((address_space(1))) const u32 gas_t;
typedef __attribute__((address_space(3))) u32 las_t;
__device__ inline void gl16(const short* g, short* l) {
    __builtin_amdgcn_global_load_lds((gas_t*)g, (las_t*)l, 16, 0, 0);
}

// ---------------------------------------------------------------------------
// Fused: all four weights -> bf16 AND LN1 in ONE dispatch (blockIdx split).
// ---------------------------------------------------------------------------
#define N4_QKV  (3 * INdim * Ddim / 4)   // 49152
#define N4_PROJ (INdim * INdim / 4)      // 16384
#define N4_W1   (HIDdim * Ddim / 4)      // 65536
#define N4_W2   (Ddim * HIDdim / 4)      // 65536
#define NCVT_BLK ((N4_QKV + N4_PROJ + N4_W1 + N4_W2) / 256)   // 768

__global__ __launch_bounds__(256) void cvt_ln1_kernel(const float* __restrict__ s0,
                                                      const float* __restrict__ s1,
                                                      const float* __restrict__ s2,
                                                      const float* __restrict__ s3,
                                                      short* __restrict__ d0,
                                                      short* __restrict__ d1,
                                                      short* __restrict__ d2,
                                                      short* __restrict__ d3,
                                                      const float* __restrict__ x,
                                                      const float* __restrict__ g,
                                                      const float* __restrict__ b,
                                                      float* __restrict__ outf,
                                                      short* __restrict__ outb) {
    const int bid = blockIdx.x;
    if (bid < NCVT_BLK) {
        int i = bid * 256 + threadIdx.x;
        const float* src; short* dst; int j;
        if (i < N4_QKV)                          { src = s0; dst = d0; j = i; }
        else if (i < N4_QKV + N4_PROJ)           { src = s1; dst = d1; j = i - N4_QKV; }
        else if (i < N4_QKV + N4_PROJ + N4_W1)   { src = s2; dst = d2; j = i - N4_QKV - N4_PROJ; }
        else                                     { src = s3; dst = d3; j = i - N4_QKV - N4_PROJ - N4_W1; }
        float4 v = ((const float4*)src)[j];
        bf16x4 bb;
        bb[0] = f2bf(v.x); bb[1] = f2bf(v.y); bb[2] = f2bf(v.z); bb[3] = f2bf(v.w);
        ((bf16x4*)dst)[j] = bb;
    } else {
        int w = threadIdx.x >> 6, lane = threadIdx.x & 63;
        int row = (bid - NCVT_BLK) * 4 + w;
        float4 v = ((const float4*)x)[(size_t)row * 64 + lane];
        float s  = (v.x + v.y) + (v.z + v.w);
        float s2 = (v.x * v.x + v.y * v.y) + (v.z * v.z + v.w * v.w);
        #pragma unroll
        for (int off = 32; off; off >>= 1) {
            s  += __shfl_xor(s,  off, 64);
            s2 += __shfl_xor(s2, off, 64);
        }
        float mu   = s * (1.0f / Ddim);
        float var  = s2 * (1.0f / Ddim) - mu * mu;
        float rstd = rsqrtf(var + 1e-5f);
        float4 gg = ((const float4*)g)[lane];
        float4 bb = ((const float4*)b)[lane];
        float4 r;
        r.x = (v.x - mu) * rstd * gg.x + bb.x;
        r.y = (v.y - mu) * rstd * gg.y + bb.y;
        r.z = (v.z - mu) * rstd * gg.z + bb.z;
        r.w = (v.w - mu) * rstd * gg.w + bb.w;
        if (outf) ((float4*)outf)[(size_t)row * 64 + lane] = r;
        bf16x4 rb;
        rb[0] = f2bf(r.x); rb[1] = f2bf(r.y); rb[2] = f2bf(r.z); rb[3] = f2bf(r.w);
        ((bf16x4*)outb)[(size_t)row * 64 + lane] = rb;
    }
}

// ---------------------------------------------------------------------------
// LayerNorm, wave-per-row (4 rows/block), float4 vectorized.  (LN2)
// ---------------------------------------------------------------------------
__global__ __launch_bounds__(256) void ln4_kernel(const float* __restrict__ x,
                                                  const float* __restrict__ g,
                                                  const float* __restrict__ b,
                                                  float* __restrict__ outf,
                                                  short* __restrict__ outb) {
    int w = threadIdx.x >> 6, lane = threadIdx.x & 63;
    int row = blockIdx.x * 4 + w;
    float4 v = ((const float4*)x)[(size_t)row * 64 + lane];
    float s  = (v.x + v.y) + (v.z + v.w);
    float s2 = (v.x * v.x + v.y * v.y) + (v.z * v.z + v.w * v.w);
    #pragma unroll
    for (int off = 32; off; off >>= 1) {
        s  += __shfl_xor(s,  off, 64);
        s2 += __shfl_xor(s2, off, 64);
    }
    float mu   = s * (1.0f / Ddim);
    float var  = s2 * (1.0f / Ddim) - mu * mu;
    float rstd = rsqrtf(var + 1e-5f);
    float4 gg = ((const float4*)g)[lane];
    float4 bb = ((const float4*)b)[lane];
    float4 r;
    r.x = (v.x - mu) * rstd * gg.x + bb.x;
    r.y = (v.y - mu) * rstd * gg.y + bb.y;
    r.z = (v.z - mu) * rstd * gg.z + bb.z;
    r.w = (v.w - mu) * rstd * gg.w + bb.w;
    if (outf) ((float4*)outf)[(size_t)row * 64 + lane] = r;
    bf16x4 rb;
    rb[0] = f2bf(r.x); rb[1] = f2bf(r.y); rb[2] = f2bf(r.z); rb[3] = f2bf(r.w);
    ((bf16x4*)outb)[(size_t)row * 64 + lane] = rb;
}

// ---------------------------------------------------------------------------
// Pipelined m97 GEMM: 128x128 tile, BK=64, gl16 staging, DOUBLE-buffered LDS
// (64KB - free: measured occupancy was already ~2 blocks/CU at 32KB), and
// T4 counted-vmcnt waits: the mid-loop wait is vmcnt(8) (= next tile's loads
// stay in flight), never a full drain. Read-chunk XOR swizzle c^(row&7) with
// inverse-swizzled per-lane source (both-sides rule, verified R12).
// ---------------------------------------------------------------------------
#define EPI_NONE 0
#define EPI_PROJ 1
#define EPI_GELU 2
#define EPI_RES  3
#define EPI_QKV  4

#define SCALE2Q 0.25505654249892417f   // 32^-0.5 * log2(e)

template <int EPI>
__global__ __launch_bounds__(256) void gemm128p(const short* __restrict__ A,
                                                const short* __restrict__ W,
                                                short* __restrict__ C,
                                                int N, int K,
                                                const float* __restrict__ bias) {
    __shared__ __attribute__((aligned(16))) short As[2][128 * 64];
    __shared__ __attribute__((aligned(16))) short Bs[2][128 * 64];
    const int tid = threadIdx.x, w = tid >> 6, lane = tid & 63;
    const int col = lane & 31;
    const int half_id = lane >> 5;

    // bijective XCD swizzle (total grid size is a multiple of 8)
    const int nbx = gridDim.x;
    const int flat = blockIdx.y * nbx + blockIdx.x;
    const int cpx = (nbx * (int)gridDim.y) >> 3;
    const int swz = (flat & 7) * cpx + (flat >> 3);
    const int m0 = (swz / nbx) * 128, n0 = (swz % nbx) * 128;

    // wave tiling: 2x2 waves, each owns 64x64 (2x2 of 32x32)
    const int wm = (w & 1) * 64;
    const int wn = (w >> 1) * 64;

    f32x16 acc[2][2];
    #pragma unroll
    for (int i = 0; i < 2; ++i) { acc[i][0] = 0.0f; acc[i][1] = 0.0f; }

    // staging: wave w stages A rows w*32..+31 and B rows w*32..+31, BK=64.
    // one gl16 covers 8 rows; 4 per matrix -> 8 gl16 per wave per stage.
    const int lrow = lane >> 3;
    const int lchk = (lane & 7) ^ lrow;   // inverse of read swizzle
    const short* gA = &A[(size_t)(m0 + w * 32 + lrow) * K + lchk * 8];
    const short* gB = &W[(size_t)(n0 + w * 32 + lrow) * K + lchk * 8];

    const int T = K >> 6;   // 4 for K=256

    auto STAGE = [&](int buf, int kt) {
        short* lA = &As[buf][(w * 32) * 64];
        short* lB = &Bs[buf][(w * 32) * 64];
        #pragma unroll
        for (int i = 0; i < 4; ++i) {
            gl16(gA + (size_t)(i * 8) * K + kt * 64, lA + i * 512);
            gl16(gB + (size_t)(i * 8) * K + kt * 64, lB + i * 512);
        }
    };

    // prologue: stage t0 and t1; wait only t0 (8 of 16 outstanding)
    STAGE(0, 0);
    if (T > 1) {
        STAGE(1, 1);
        asm volatile("s_waitcnt vmcnt(8)" ::: "memory");
    } else {
        asm volatile("s_waitcnt vmcnt(0)" ::: "memory");
    }
    __builtin_amdgcn_s_barrier();

    for (int kt = 0; kt < T; ++kt) {
        const int buf = kt & 1;
        #pragma unroll
        for (int ks = 0; ks < 4; ++ks) {
            const int c = ks * 2 + half_id;   // global chunk 0..7
            bf16x8 af[2], bfv[2];
            #pragma unroll
            for (int t = 0; t < 2; ++t) {
                const int Ra = wm + t * 32 + col;
                af[t] = *(const bf16x8*)&As[buf][Ra * 64 + ((c ^ (Ra & 7)) * 8)];
                const int Rb = wn + t * 32 + col;
                bfv[t] = *(const bf16x8*)&Bs[buf][Rb * 64 + ((c ^ (Rb & 7)) * 8)];
            }
            #pragma unroll
            for (int tm = 0; tm < 2; ++tm)
                #pragma unroll
                for (int tn = 0; tn < 2; ++tn)
                    acc[tm][tn] = __builtin_amdgcn_mfma_f32_32x32x16_bf16(
                        af[tm], bfv[tn], acc[tm][tn], 0, 0, 0);
        }
        // all my LDS reads done before anyone overwrites this buffer
        asm volatile("s_waitcnt lgkmcnt(0)" ::: "memory");
        __builtin_amdgcn_s_barrier();
        if (kt + 2 < T) {
            STAGE(buf, kt + 2);   // outstanding: (kt+1)'s 8 + (kt+2)'s 8
            asm volatile("s_waitcnt vmcnt(8)" ::: "memory");   // (kt+1) landed
        } else {
            asm volatile("s_waitcnt vmcnt(0)" ::: "memory");   // tail drain
        }
        __builtin_amdgcn_s_barrier();
    }

    #pragma unroll
    for (int tm = 0; tm < 2; ++tm) {
        #pragma unroll
        for (int r = 0; r < 16; ++r) {
            int row = m0 + wm + tm * 32 + (r & 3) + 8 * (r >> 2) + 4 * half_id;
            #pragma unroll
            for (int tn = 0; tn < 2; ++tn) {
                int cn = n0 + wn + tn * 32 + col;
                float v = acc[tm][tn][r];
                if (EPI == EPI_QKV && cn < 256) v *= SCALE2Q;
                if (EPI == EPI_GELU) v = gelu_exact(v + bias[cn]);
                C[(size_t)row * N + cn] = f2bf(v);
            }
        }
    }
}

// ---------------------------------------------------------------------------
// Reg-staged GEMM, BM=64, BK=32 (R9-measured config) for PROJ and RES.
// COMB=true fuses the attention j-partition combine into A staging (PROJ;
// valid because BK=32 == head dim, so kt IS the head index).
// ---------------------------------------------------------------------------
#define GPAD32 40   // shorts per LDS row (32 data + 8 pad, 16B-aligned rows)

__device__ inline bf16x8 comb8(bf16x8 a, bf16x8 b, float rl) {
    bf16x8 r;
    #pragma unroll
    for (int i = 0; i < 8; ++i) r[i] = f2bf((bf2f(a[i]) + bf2f(b[i])) * rl);
    return r;
}

template <int EPI, int BN, bool COMB>
__global__ __launch_bounds__(256) void gemm_mfma(const short* __restrict__ A,
                                                 const short* __restrict__ W,
                                                 void* __restrict__ Cv,
                                                 int M, int N, int K,
                                                 const float* __restrict__ bias,
                                                 const float* __restrict__ add1,
                                                 const float* __restrict__ add2,
                                                 const float* __restrict__ lpc) {
    __shared__ short As[64 * GPAD32];
    __shared__ short Bs[BN * GPAD32];
    const int tid = threadIdx.x, w = tid >> 6, lane = tid & 63;
    const int col = lane & 31;
    const int half_id = lane >> 5;

    const int nbx = gridDim.x;
    const int flat = blockIdx.y * nbx + blockIdx.x;
    const int cpx = (nbx * (int)gridDim.y) >> 3;
    const int swz = (flat & 7) * cpx + (flat >> 3);
    const int m0 = (swz / nbx) * 64, n0 = (swz % nbx) * BN;

    const int wm = (w & 1) * 32;
    const int wn = (BN == 128) ? (w >> 1) * 64 : (w >> 1) * 32;
    constexpr int TN = (BN == 128) ? 2 : 1;

    f32x16 acc[TN];
    #pragma unroll
    for (int t = 0; t < TN; ++t) acc[t] = 0.0f;

    const int sra = tid >> 2, ssa = (tid & 3) * 8;
    const int srb = (BN == 128) ? (tid >> 1) : (tid >> 2);
    const int ssb = (BN == 128) ? (tid & 1) * 16 : (tid & 3) * 8;
    constexpr int NB = (BN == 128) ? 2 : 1;

    const short* pAsrc = &A[(size_t)(m0 + sra) * K + ssa];
    const short* pBsrc = &W[(size_t)(n0 + srb) * K + ssb];
    const float* lpr0 = COMB ? (lpc + (size_t)(m0 + sra) * 8) : nullptr;
    const float* lpr1 = COMB ? (lpr0 + (size_t)Tdim * 8) : nullptr;

    bf16x8 pa, pa2, pb[NB];
    float pl = 0.0f;
    pa = *(const bf16x8*)&pAsrc[0];
    if constexpr (COMB) {
        pa2 = *(const bf16x8*)(pAsrc + (size_t)Tdim * 256);
        pl = lpr0[0] + lpr1[0];
    }
    #pragma unroll
    for (int j = 0; j < NB; ++j) pb[j] = *(const bf16x8*)&pBsrc[j * 8];

    const int T = K >> 5;
    for (int kt = 0; kt < T; ++kt) {
        __syncthreads();
        {
            bf16x8 av = pa;
            if constexpr (COMB) av = comb8(pa, pa2, 1.0f / pl);
            *(bf16x8*)&As[sra * GPAD32 + ssa] = av;
        }
        #pragma unroll
        for (int j = 0; j < NB; ++j) *(bf16x8*)&Bs[srb * GPAD32 + ssb + j * 8] = pb[j];
        __syncthreads();

        if (kt + 1 < T) {
            const short* a = pAsrc + (kt + 1) * 32;
            const short* b = pBsrc + (kt + 1) * 32;
            pa = *(const bf16x8*)&a[0];
            if constexpr (COMB) {
                pa2 = *(const bf16x8*)(a + (size_t)Tdim * 256);
                pl = lpr0[kt + 1] + lpr1[kt + 1];
            }
            #pragma unroll
            for (int j = 0; j < NB; ++j) pb[j] = *(const bf16x8*)&b[j * 8];
        }

        #pragma unroll
        for (int ks = 0; ks < 2; ++ks) {
            bf16x8 af = *(const bf16x8*)&As[(wm + col) * GPAD32 + ks * 16 + half_id * 8];
            bf16x8 bfv[TN];
            #pragma unroll
            for (int t = 0; t < TN; ++t)
                bfv[t] = *(const bf16x8*)&Bs[(wn + t * 32 + col) * GPAD32 + ks * 16 + half_id * 8];
            #pragma unroll
            for (int t = 0; t < TN; ++t)
                acc[t] = __builtin_amdgcn_mfma_f32_32x32x16_bf16(af, bfv[t], acc[t], 0, 0, 0);
        }
    }

    float* Cf = (float*)Cv;
    short* Cb = (short*)Cv;
    #pragma unroll
    for (int r = 0; r < 16; ++r) {
        int row = m0 + wm + (r & 3) + 8 * (r >> 2) + 4 * half_id;
        #pragma unroll
        for (int t = 0; t < TN; ++t) {
            int cn = n0 + wn + t * 32 + col;
            size_t off = (size_t)row * N + cn;
            float v = acc[t][r];
            if (EPI != EPI_NONE && EPI != EPI_QKV) v += bias[cn];
            if (EPI == EPI_GELU) v = gelu_exact(v);
            if (EPI == EPI_PROJ) v += add1[off] + add2[off];
            if (EPI == EPI_RES)  v += add1[off];
            if (EPI == EPI_PROJ || EPI == EPI_RES) Cf[off] = v;
            else                                   Cb[off] = f2bf(v);
        }
    }
}

// ---------------------------------------------------------------------------
// One-time V transpose: qkv[b][n][512+head*32+d] -> vT[(bh*32+d)][n].
// ---------------------------------------------------------------------------
#define VTPAD 136

__global__ __launch_bounds__(256) void vtrans_kernel(const short* __restrict__ qkv,
                                                     short* __restrict__ vT) {
    __shared__ short Tl[32 * VTPAD];
    const int tid = threadIdx.x;
    const int bh = blockIdx.x, c = blockIdx.y;
    const int b = bh >> 3, head = bh & 7;
    {
        int r = tid >> 1, hv = tid & 1;
        const short* src = qkv + (size_t)b * Ndim * 768 + (size_t)(c * 128 + r) * 768
                           + 512 + head * 32 + hv * 16;
        bf16x8 v0 = *(const bf16x8*)&src[0];
        bf16x8 v1 = *(const bf16x8*)&src[8];
        #pragma unroll
        for (int i = 0; i < 8; ++i) {
            Tl[(hv * 16 + i) * VTPAD + r]     = v0[i];
            Tl[(hv * 16 + 8 + i) * VTPAD + r] = v1[i];
        }
    }
    __syncthreads();
    {
        int d = tid >> 3, j16 = (tid & 7) * 16;
        short* dst = vT + (size_t)(bh * 32 + d) * Ndim + c * 128 + j16;
        *(bf16x8*)&dst[0] = *(const bf16x8*)&Tl[d * VTPAD + j16];
        *(bf16x8*)&dst[8] = *(const bf16x8*)&Tl[d * VTPAD + j16 + 8];
    }
}

// ---------------------------------------------------------------------------
// MFMA attention, j-split flash (maxless -> partials additive). Partials bf16.
// In-register P relayout (cvt_pk + permlane32_swap), T14 async staging,
// jt software pipeline, 1D grid with XCD-locality decode.
// ---------------------------------------------------------------------------
#define KVPAD 40
#define CHUNK 128

__global__ __launch_bounds__(256) void attn_mfma_kernel(const short* __restrict__ qkv,
                                                        const short* __restrict__ vT,
                                                        short* __restrict__ opart,
                                                        float* __restrict__ lpart) {
    __shared__ short Ks[CHUNK * KVPAD];
    __shared__ short Vt[32 * VTPAD];

    const int tid = threadIdx.x;
    const int w = tid >> 6;
    const int lane = tid & 63;
    const int col = lane & 31;
    const int half_id = lane >> 5;

    const int id = blockIdx.x;            // 0..2047
    const int xcd = id & 7;
    const int s_ = id >> 3;               // 0..255
    const int bh = ((s_ >> 4) << 3) | xcd; // 16 bh per XCD
    const int qp = s_ & 15;
    const int qblk = qp & 7;
    const int part = qp >> 3;

    const int b = bh >> 3, head = bh & 7;
    const int q0w = qblk * 128 + w * 32;

    const size_t qkvb = (size_t)b * Ndim * 768;
    short* op = opart + (size_t)part * Tdim * 256;
    float* lp = lpart + (size_t)part * Tdim * 8;

    const int sr = tid >> 1, shv = tid & 1;
    const short* ksrc = qkv + qkvb + (size_t)sr * 768 + 256 + head * 32 + shv * 16;
    const int sd = tid >> 3, sj16 = (tid & 7) * 16;
    const short* vsrc = vT + (size_t)(bh * 32 + sd) * Ndim + sj16;

    bf16x8 qf[2];
    {
        const short* qrow = qkv + qkvb + (size_t)(q0w + col) * 768 + head * 32;
        #pragma unroll
        for (int kh = 0; kh < 2; ++kh)
            qf[kh] = *(const bf16x8*)&qrow[kh * 16 + half_id * 8];
    }

    bf16x8 vone;
    #pragma unroll
    for (int i = 0; i < 8; ++i) vone[i] = (short)0x3F80;   // bf16 1.0

    f32x16 o_acc = 0.0f, l_acc = 0.0f;

    const int c0 = part * 4;

    bf16x8 rk0, rk1, rv0, rv1;
    {
        const short* kp = ksrc + (size_t)(c0 * CHUNK) * 768;
        rk0 = *(const bf16x8*)&kp[0];
        rk1 = *(const bf16x8*)&kp[8];
        const short* vp = vsrc + c0 * CHUNK;
        rv0 = *(const bf16x8*)&vp[0];
        rv1 = *(const bf16x8*)&vp[8];
    }

    #pragma unroll
    for (int ci = 0; ci < 4; ++ci) {
        if (ci != 0) __syncthreads();
        *(bf16x8*)&Ks[sr * KVPAD + shv * 16]     = rk0;
        *(bf16x8*)&Ks[sr * KVPAD + shv * 16 + 8] = rk1;
        *(bf16x8*)&Vt[sd * VTPAD + sj16]     = rv0;
        *(bf16x8*)&Vt[sd * VTPAD + sj16 + 8] = rv1;
        __syncthreads();

        if (ci < 3) {
            const short* kp = ksrc + (size_t)((c0 + ci + 1) * CHUNK) * 768;
            rk0 = *(const bf16x8*)&kp[0];
            rk1 = *(const bf16x8*)&kp[8];
            const short* vp = vsrc + (c0 + ci + 1) * CHUNK;
            rv0 = *(const bf16x8*)&vp[0];
            rv1 = *(const bf16x8*)&vp[8];
        }

        f32x16 s_cur;
        {
            bf16x8 kf0 = *(bf16x8*)&Ks[col * KVPAD + half_id * 8];
            bf16x8 kf1 = *(bf16x8*)&Ks[col * KVPAD + 16 + half_id * 8];
            f32x16 z = 0.0f;
            z = __builtin_amdgcn_mfma_f32_32x32x16_bf16(kf0, qf[0], z, 0, 0, 0);
            z = __builtin_amdgcn_mfma_f32_32x32x16_bf16(kf1, qf[1], z, 0, 0, 0);
            s_cur = z;
        }
        #pragma unroll
        for (int jt = 0; jt < 4; ++jt) {
            f32x16 s_next;
            if (jt < 3) {
                bf16x8 kf0 = *(bf16x8*)&Ks[((jt + 1) * 32 + col) * KVPAD + half_id * 8];
                bf16x8 kf1 = *(bf16x8*)&Ks[((jt + 1) * 32 + col) * KVPAD + 16 + half_id * 8];
                f32x16 z = 0.0f;
                z = __builtin_amdgcn_mfma_f32_32x32x16_bf16(kf0, qf[0], z, 0, 0, 0);
                z = __builtin_amdgcn_mfma_f32_32x32x16_bf16(kf1, qf[1], z, 0, 0, 0);
                s_next = z;
            }

            bf16x8 vf0 = *(bf16x8*)&Vt[col * VTPAD + jt * 32 + half_id * 8];
            bf16x8 vf1 = *(bf16x8*)&Vt[col * VTPAD + jt * 32 + 16 + half_id * 8];

            u32 wd[8];
            #pragma unroll
            for (int g = 0; g < 8; ++g) {
                float e0 = fexp2(s_cur[2 * g + 0]);
                float e1 = fexp2(s_cur[2 * g + 1]);
                wd[g] = pack2bf(e0, e1);
            }
            plswap(wd[0], wd[2]); plswap(wd[1], wd[3]);
            plswap(wd[4], wd[6]); plswap(wd[5], wd[7]);

            union { u32 u[4]; bf16x8 v; } p0, p1;
            p0.u[0] = wd[0]; p0.u[1] = wd[1]; p0.u[2] = wd[2]; p0.u[3] = wd[3];
            p1.u[0] = wd[4]; p1.u[1] = wd[5]; p1.u[2] = wd[6]; p1.u[3] = wd[7];

            __builtin_amdgcn_s_setprio(1);
            o_acc = __builtin_amdgcn_mfma_f32_32x32x16_bf16(p0.v, vf0, o_acc, 0, 0, 0);
            o_acc = __builtin_amdgcn_mfma_f32_32x32x16_bf16(p1.v, vf1, o_acc, 0, 0, 0);
            l_acc = __builtin_amdgcn_mfma_f32_32x32x16_bf16(p0.v, vone, l_acc, 0, 0, 0);
            l_acc = __builtin_amdgcn_mfma_f32_32x32x16_bf16(p1.v, vone, l_acc, 0, 0, 0);
            __builtin_amdgcn_s_setprio(0);

            if (jt < 3) s_cur = s_next;
        }
    }

    #pragma unroll
    for (int r = 0; r < 16; ++r) {
        int q_r = (r & 3) + 8 * (r >> 2) + 4 * half_id;
        size_t gq = (size_t)(b * Ndim + q0w + q_r);
        op[gq * INdim + head * 32 + col] = f2bf(o_acc[r]);
    }
    if (col < 16) {
        int r = col;
        int q_r = (r & 3) + 8 * (r >> 2) + 4 * half_id;
        lp[(size_t)(b * Ndim + q0w + q_r) * 8 + head] = l_acc[r];
    }
}

// ---------------------------------------------------------------------------
// launch
// ---------------------------------------------------------------------------
extern "C" void kernel_launch(void* const* d_in, const int* in_sizes, int n_in,
                              void* d_out, int out_size, void* d_ws, size_t ws_size,
                              hipStream_t stream) {
    const float* x     = (const float*)d_in[0];
    const float* g1    = (const float*)d_in[2];
    const float* b1    = (const float*)d_in[3];
    const float* Wqkv  = (const float*)d_in[4];
    const float* Wproj = (const float*)d_in[5];
    const float* bproj = (const float*)d_in[6];
    const float* g2    = (const float*)d_in[7];
    const float* b2    = (const float*)d_in[8];
    const float* W1    = (const float*)d_in[9];
    const float* bb1   = (const float*)d_in[10];
    const float* W2    = (const float*)d_in[11];
    const float* bb2   = (const float*)d_in[12];
    float* out = (float*)d_out;

    // workspace:
    //  [0,16M)  h fp32
    //  [16,24M) h_bf
    //  [24,48M) qkv_bf (dead after attn) -> xnew fp32 [24,40M)
    //  [48,64M) opart bf16 x2 (dead after PROJ) -> mid_bf [48,80M)
    //  [80,81M) lpart fp32 [2][Tdim*8]
    //  [81,89M) vT bf16
    //  [89,91M) weights bf16
    char* ws = (char*)d_ws;
    float* h      = (float*)(ws);
    short* h_bf   = (short*)(ws + (size_t)(16u << 20));
    short* qkv_bf = (short*)(ws + (size_t)(24u << 20));
    float* xnew   = (float*)(ws + (size_t)(24u << 20));
    short* opart  = (short*)(ws + (size_t)(48u << 20));
    short* mid_bf = (short*)(ws + (size_t)(48u << 20));
    float* lpart  = (float*)(ws + (size_t)(80u << 20));
    short* vT     = (short*)(ws + (size_t)(81u << 20));
    short* wqkv_b = (short*)(ws + (size_t)(89u << 20));
    short* wproj_b= (short*)(ws + (size_t)(89u << 20) + 768 * 1024);
    short* w1_b   = (short*)(ws + (size_t)(90u << 20));
    short* w2_b   = (short*)(ws + (size_t)(90u << 20) + 512 * 1024);

    // 0+1) weights -> bf16 AND LN1 in one dispatch
    cvt_ln1_kernel<<<NCVT_BLK + Tdim / 4, 256, 0, stream>>>(
        Wqkv, Wproj, W1, W2, wqkv_b, wproj_b, w1_b, w2_b,
        x, g1, b1, h, h_bf);
    // 2) qkv_bf = h_bf @ Wqkv^T (pipelined gl16 template, counted vmcnt)
    gemm128p<EPI_QKV><<<dim3(768 / 128, Tdim / 128), 256, 0, stream>>>(
        h_bf, wqkv_b, qkv_bf, 768, 256, nullptr);
    // 2b) V transpose (once)
    vtrans_kernel<<<dim3(Bdim * Hdim, Ndim / 128), 256, 0, stream>>>(qkv_bf, vT);
    // 3) attention partials (j-split x2), XCD-locality 1D grid
    attn_mfma_kernel<<<2048, 256, 0, stream>>>(qkv_bf, vT, opart, lpart);
    // 4) xnew = ((O0+O1)/l) @ Wproj^T + bproj + h + x   (combine fused, reg-staged)
    gemm_mfma<EPI_PROJ, 64, true><<<dim3(256 / 64, Tdim / 64), 256, 0, stream>>>(
        opart, wproj_b, xnew, Tdim, 256, 256, bproj, h, x, lpart);
    // 5) LN2: xnew -> h_bf
    ln4_kernel<<<Tdim / 4, 256, 0, stream>>>(xnew, g2, b2, nullptr, h_bf);
    // 6) mid_bf = gelu(h2 @ W1^T + bb1)   (pipelined template)
    gemm128p<EPI_GELU><<<dim3(1024 / 128, Tdim / 128), 256, 0, stream>>>(
        h_bf, w1_b, mid_bf, 1024, 256, bb1);
    // 7) out = xnew + mid @ W2^T + bb2   (reg-staged, R9 config)
    gemm_mfma<EPI_RES, 64, false><<<dim3(256 / 64, Tdim / 64), 256, 0, stream>>>(
        mid_bf, w2_b, out, Tdim, 256, 1024, bb2, xnew, nullptr, nullptr);
}

// Round 14
// 208.002 us; speedup vs baseline: 1.0212x; 1.0212x over previous
//
#include <hip/hip_runtime.h>
#include <hip/hip_bf16.h>
#include <math.h>

// Shapes (fixed by the reference)
#define Bdim 16
#define Ndim 1024
#define Ddim 256
#define Hdim 8
#define HDdim 32
#define INdim 256
#define HIDdim 1024
#define Tdim (Bdim * Ndim)   // 16384 rows

typedef __attribute__((ext_vector_type(8)))  short bf16x8;
typedef __attribute__((ext_vector_type(4)))  short bf16x4;
typedef __attribute__((ext_vector_type(16))) float f32x16;
typedef unsigned int u32;

__device__ inline short f2bf(float x) {
    union { __hip_bfloat16 b; short s; } u;
    u.b = __float2bfloat16(x);
    return u.s;
}

__device__ inline float bf2f(short s) {
    return __uint_as_float(((u32)(unsigned short)s) << 16);
}

// raw v_exp_f32 (scores are bounded; no libm range handling needed)
__device__ inline float fexp2(float x) {
#if __has_builtin(__builtin_amdgcn_exp2f)
    return __builtin_amdgcn_exp2f(x);
#else
    return exp2f(x);
#endif
}

// pack two f32 -> two bf16 in a u32
__device__ inline u32 pack2bf(float a, float b) {
#if __has_builtin(__builtin_amdgcn_cvt_pk_bf16_f32)
    typedef __attribute__((ext_vector_type(2))) __bf16 bf16x2_t;
    union { bf16x2_t v; u32 u; } c;
    c.v = __builtin_amdgcn_cvt_pk_bf16_f32(a, b);
    return c.u;
#else
    u32 ua = __float_as_uint(a), ub = __float_as_uint(b);
    return ((ua + 0x8000u) >> 16) | ((ub + 0x8000u) & 0xffff0000u);
#endif
}

// v_permlane32_swap_b32: after execution a = {a.lo32, b.lo32}, b = {a.hi32, b.hi32}
__device__ inline void plswap(u32 &a, u32 &b) {
    asm volatile("v_permlane32_swap_b32 %0, %1" : "+v"(a), "+v"(b));
}

__device__ inline float gelu_exact(float v) {
    return 0.5f * v * (1.0f + erff(v * 0.70710678118654752f));
}

// direct global->LDS copy, 16B per lane. LDS dest is wave-uniform base +
// lane*16 (HW-enforced); global src is per-lane.
typedef __attribute__((address_space(1))) const u32 gas_t;
typedef __attribute__((address_space(3))) u32 las_t;
__device__ inline void gl16(const short* g, short* l) {
    __builtin_amdgcn_global_load_lds((gas_t*)g, (las_t*)l, 16, 0, 0);
}

// ---------------------------------------------------------------------------
// Fused: all four weights -> bf16 AND LN1 in ONE dispatch (blockIdx split).
// ---------------------------------------------------------------------------
#define N4_QKV  (3 * INdim * Ddim / 4)   // 49152
#define N4_PROJ (INdim * INdim / 4)      // 16384
#define N4_W1   (HIDdim * Ddim / 4)      // 65536
#define N4_W2   (Ddim * HIDdim / 4)      // 65536
#define NCVT_BLK ((N4_QKV + N4_PROJ + N4_W1 + N4_W2) / 256)   // 768

__global__ __launch_bounds__(256) void cvt_ln1_kernel(const float* __restrict__ s0,
                                                      const float* __restrict__ s1,
                                                      const float* __restrict__ s2,
                                                      const float* __restrict__ s3,
                                                      short* __restrict__ d0,
                                                      short* __restrict__ d1,
                                                      short* __restrict__ d2,
                                                      short* __restrict__ d3,
                                                      const float* __restrict__ x,
                                                      const float* __restrict__ g,
                                                      const float* __restrict__ b,
                                                      float* __restrict__ outf,
                                                      short* __restrict__ outb) {
    const int bid = blockIdx.x;
    if (bid < NCVT_BLK) {
        int i = bid * 256 + threadIdx.x;
        const float* src; short* dst; int j;
        if (i < N4_QKV)                          { src = s0; dst = d0; j = i; }
        else if (i < N4_QKV + N4_PROJ)           { src = s1; dst = d1; j = i - N4_QKV; }
        else if (i < N4_QKV + N4_PROJ + N4_W1)   { src = s2; dst = d2; j = i - N4_QKV - N4_PROJ; }
        else                                     { src = s3; dst = d3; j = i - N4_QKV - N4_PROJ - N4_W1; }
        float4 v = ((const float4*)src)[j];
        bf16x4 bb;
        bb[0] = f2bf(v.x); bb[1] = f2bf(v.y); bb[2] = f2bf(v.z); bb[3] = f2bf(v.w);
        ((bf16x4*)dst)[j] = bb;
    } else {
        int w = threadIdx.x >> 6, lane = threadIdx.x & 63;
        int row = (bid - NCVT_BLK) * 4 + w;
        float4 v = ((const float4*)x)[(size_t)row * 64 + lane];
        float s  = (v.x + v.y) + (v.z + v.w);
        float s2 = (v.x * v.x + v.y * v.y) + (v.z * v.z + v.w * v.w);
        #pragma unroll
        for (int off = 32; off; off >>= 1) {
            s  += __shfl_xor(s,  off, 64);
            s2 += __shfl_xor(s2, off, 64);
        }
        float mu   = s * (1.0f / Ddim);
        float var  = s2 * (1.0f / Ddim) - mu * mu;
        float rstd = rsqrtf(var + 1e-5f);
        float4 gg = ((const float4*)g)[lane];
        float4 bb = ((const float4*)b)[lane];
        float4 r;
        r.x = (v.x - mu) * rstd * gg.x + bb.x;
        r.y = (v.y - mu) * rstd * gg.y + bb.y;
        r.z = (v.z - mu) * rstd * gg.z + bb.z;
        r.w = (v.w - mu) * rstd * gg.w + bb.w;
        if (outf) ((float4*)outf)[(size_t)row * 64 + lane] = r;
        bf16x4 rb;
        rb[0] = f2bf(r.x); rb[1] = f2bf(r.y); rb[2] = f2bf(r.z); rb[3] = f2bf(r.w);
        ((bf16x4*)outb)[(size_t)row * 64 + lane] = rb;
    }
}

// ---------------------------------------------------------------------------
// LayerNorm, wave-per-row (4 rows/block), float4 vectorized.  (LN2)
// ---------------------------------------------------------------------------
__global__ __launch_bounds__(256) void ln4_kernel(const float* __restrict__ x,
                                                  const float* __restrict__ g,
                                                  const float* __restrict__ b,
                                                  float* __restrict__ outf,
                                                  short* __restrict__ outb) {
    int w = threadIdx.x >> 6, lane = threadIdx.x & 63;
    int row = blockIdx.x * 4 + w;
    float4 v = ((const float4*)x)[(size_t)row * 64 + lane];
    float s  = (v.x + v.y) + (v.z + v.w);
    float s2 = (v.x * v.x + v.y * v.y) + (v.z * v.z + v.w * v.w);
    #pragma unroll
    for (int off = 32; off; off >>= 1) {
        s  += __shfl_xor(s,  off, 64);
        s2 += __shfl_xor(s2, off, 64);
    }
    float mu   = s * (1.0f / Ddim);
    float var  = s2 * (1.0f / Ddim) - mu * mu;
    float rstd = rsqrtf(var + 1e-5f);
    float4 gg = ((const float4*)g)[lane];
    float4 bb = ((const float4*)b)[lane];
    float4 r;
    r.x = (v.x - mu) * rstd * gg.x + bb.x;
    r.y = (v.y - mu) * rstd * gg.y + bb.y;
    r.z = (v.z - mu) * rstd * gg.z + bb.z;
    r.w = (v.w - mu) * rstd * gg.w + bb.w;
    if (outf) ((float4*)outf)[(size_t)row * 64 + lane] = r;
    bf16x4 rb;
    rb[0] = f2bf(r.x); rb[1] = f2bf(r.y); rb[2] = f2bf(r.z); rb[3] = f2bf(r.w);
    ((bf16x4*)outb)[(size_t)row * 64 + lane] = rb;
}

// ---------------------------------------------------------------------------
// Pipelined m97 GEMM: 128x128 tile, BK=64, gl16 staging, double-buffered LDS,
// counted-vmcnt waits (next tile's loads stay in flight; drain only at tail).
// Read-chunk XOR swizzle c^(row&7) with inverse-swizzled per-lane source.
// ---------------------------------------------------------------------------
#define EPI_NONE 0
#define EPI_PROJ 1
#define EPI_GELU 2
#define EPI_RES  3
#define EPI_QKV  4

#define SCALE2Q 0.25505654249892417f   // 32^-0.5 * log2(e)

template <int EPI>
__global__ __launch_bounds__(256) void gemm128p(const short* __restrict__ A,
                                                const short* __restrict__ W,
                                                short* __restrict__ C,
                                                int N, int K,
                                                const float* __restrict__ bias) {
    __shared__ __attribute__((aligned(16))) short As[2][128 * 64];
    __shared__ __attribute__((aligned(16))) short Bs[2][128 * 64];
    const int tid = threadIdx.x, w = tid >> 6, lane = tid & 63;
    const int col = lane & 31;
    const int half_id = lane >> 5;

    // bijective XCD swizzle (total grid size is a multiple of 8)
    const int nbx = gridDim.x;
    const int flat = blockIdx.y * nbx + blockIdx.x;
    const int cpx = (nbx * (int)gridDim.y) >> 3;
    const int swz = (flat & 7) * cpx + (flat >> 3);
    const int m0 = (swz / nbx) * 128, n0 = (swz % nbx) * 128;

    // wave tiling: 2x2 waves, each owns 64x64 (2x2 of 32x32)
    const int wm = (w & 1) * 64;
    const int wn = (w >> 1) * 64;

    f32x16 acc[2][2];
    #pragma unroll
    for (int i = 0; i < 2; ++i) { acc[i][0] = 0.0f; acc[i][1] = 0.0f; }

    const int lrow = lane >> 3;
    const int lchk = (lane & 7) ^ lrow;   // inverse of read swizzle
    const short* gA = &A[(size_t)(m0 + w * 32 + lrow) * K + lchk * 8];
    const short* gB = &W[(size_t)(n0 + w * 32 + lrow) * K + lchk * 8];

    const int T = K >> 6;   // 4 for K=256

    auto STAGE = [&](int buf, int kt) {
        short* lA = &As[buf][(w * 32) * 64];
        short* lB = &Bs[buf][(w * 32) * 64];
        #pragma unroll
        for (int i = 0; i < 4; ++i) {
            gl16(gA + (size_t)(i * 8) * K + kt * 64, lA + i * 512);
            gl16(gB + (size_t)(i * 8) * K + kt * 64, lB + i * 512);
        }
    };

    STAGE(0, 0);
    if (T > 1) {
        STAGE(1, 1);
        asm volatile("s_waitcnt vmcnt(8)" ::: "memory");
    } else {
        asm volatile("s_waitcnt vmcnt(0)" ::: "memory");
    }
    __builtin_amdgcn_s_barrier();

    for (int kt = 0; kt < T; ++kt) {
        const int buf = kt & 1;
        #pragma unroll
        for (int ks = 0; ks < 4; ++ks) {
            const int c = ks * 2 + half_id;   // global chunk 0..7
            bf16x8 af[2], bfv[2];
            #pragma unroll
            for (int t = 0; t < 2; ++t) {
                const int Ra = wm + t * 32 + col;
                af[t] = *(const bf16x8*)&As[buf][Ra * 64 + ((c ^ (Ra & 7)) * 8)];
                const int Rb = wn + t * 32 + col;
                bfv[t] = *(const bf16x8*)&Bs[buf][Rb * 64 + ((c ^ (Rb & 7)) * 8)];
            }
            #pragma unroll
            for (int tm = 0; tm < 2; ++tm)
                #pragma unroll
                for (int tn = 0; tn < 2; ++tn)
                    acc[tm][tn] = __builtin_amdgcn_mfma_f32_32x32x16_bf16(
                        af[tm], bfv[tn], acc[tm][tn], 0, 0, 0);
        }
        asm volatile("s_waitcnt lgkmcnt(0)" ::: "memory");
        __builtin_amdgcn_s_barrier();
        if (kt + 2 < T) {
            STAGE(buf, kt + 2);
            asm volatile("s_waitcnt vmcnt(8)" ::: "memory");
        } else {
            asm volatile("s_waitcnt vmcnt(0)" ::: "memory");
        }
        __builtin_amdgcn_s_barrier();
    }

    #pragma unroll
    for (int tm = 0; tm < 2; ++tm) {
        #pragma unroll
        for (int r = 0; r < 16; ++r) {
            int row = m0 + wm + tm * 32 + (r & 3) + 8 * (r >> 2) + 4 * half_id;
            #pragma unroll
            for (int tn = 0; tn < 2; ++tn) {
                int cn = n0 + wn + tn * 32 + col;
                float v = acc[tm][tn][r];
                if (EPI == EPI_QKV && cn < 256) v *= SCALE2Q;
                if (EPI == EPI_GELU) v = gelu_exact(v + bias[cn]);
                C[(size_t)row * N + cn] = f2bf(v);
            }
        }
    }
}

// ---------------------------------------------------------------------------
// Reg-staged GEMM, BM=64, BK=32 (R9-measured config) for PROJ and RES.
// ---------------------------------------------------------------------------
#define GPAD32 40   // shorts per LDS row (32 data + 8 pad, 16B-aligned rows)

template <int EPI, int BN>
__global__ __launch_bounds__(256) void gemm_mfma(const short* __restrict__ A,
                                                 const short* __restrict__ W,
                                                 void* __restrict__ Cv,
                                                 int M, int N, int K,
                                                 const float* __restrict__ bias,
                                                 const float* __restrict__ add1,
                                                 const float* __restrict__ add2) {
    __shared__ short As[64 * GPAD32];
    __shared__ short Bs[BN * GPAD32];
    const int tid = threadIdx.x, w = tid >> 6, lane = tid & 63;
    const int col = lane & 31;
    const int half_id = lane >> 5;

    const int nbx = gridDim.x;
    const int flat = blockIdx.y * nbx + blockIdx.x;
    const int cpx = (nbx * (int)gridDim.y) >> 3;
    const int swz = (flat & 7) * cpx + (flat >> 3);
    const int m0 = (swz / nbx) * 64, n0 = (swz % nbx) * BN;

    const int wm = (w & 1) * 32;
    const int wn = (BN == 128) ? (w >> 1) * 64 : (w >> 1) * 32;
    constexpr int TN = (BN == 128) ? 2 : 1;

    f32x16 acc[TN];
    #pragma unroll
    for (int t = 0; t < TN; ++t) acc[t] = 0.0f;

    const int sra = tid >> 2, ssa = (tid & 3) * 8;
    const int srb = (BN == 128) ? (tid >> 1) : (tid >> 2);
    const int ssb = (BN == 128) ? (tid & 1) * 16 : (tid & 3) * 8;
    constexpr int NB = (BN == 128) ? 2 : 1;

    const short* pAsrc = &A[(size_t)(m0 + sra) * K + ssa];
    const short* pBsrc = &W[(size_t)(n0 + srb) * K + ssb];

    bf16x8 pa, pb[NB];
    pa = *(const bf16x8*)&pAsrc[0];
    #pragma unroll
    for (int j = 0; j < NB; ++j) pb[j] = *(const bf16x8*)&pBsrc[j * 8];

    const int T = K >> 5;
    for (int kt = 0; kt < T; ++kt) {
        __syncthreads();
        *(bf16x8*)&As[sra * GPAD32 + ssa] = pa;
        #pragma unroll
        for (int j = 0; j < NB; ++j) *(bf16x8*)&Bs[srb * GPAD32 + ssb + j * 8] = pb[j];
        __syncthreads();

        if (kt + 1 < T) {
            const short* a = pAsrc + (kt + 1) * 32;
            const short* b = pBsrc + (kt + 1) * 32;
            pa = *(const bf16x8*)&a[0];
            #pragma unroll
            for (int j = 0; j < NB; ++j) pb[j] = *(const bf16x8*)&b[j * 8];
        }

        #pragma unroll
        for (int ks = 0; ks < 2; ++ks) {
            bf16x8 af = *(const bf16x8*)&As[(wm + col) * GPAD32 + ks * 16 + half_id * 8];
            bf16x8 bfv[TN];
            #pragma unroll
            for (int t = 0; t < TN; ++t)
                bfv[t] = *(const bf16x8*)&Bs[(wn + t * 32 + col) * GPAD32 + ks * 16 + half_id * 8];
            #pragma unroll
            for (int t = 0; t < TN; ++t)
                acc[t] = __builtin_amdgcn_mfma_f32_32x32x16_bf16(af, bfv[t], acc[t], 0, 0, 0);
        }
    }

    float* Cf = (float*)Cv;
    short* Cb = (short*)Cv;
    #pragma unroll
    for (int r = 0; r < 16; ++r) {
        int row = m0 + wm + (r & 3) + 8 * (r >> 2) + 4 * half_id;
        #pragma unroll
        for (int t = 0; t < TN; ++t) {
            int cn = n0 + wn + t * 32 + col;
            size_t off = (size_t)row * N + cn;
            float v = acc[t][r];
            if (EPI != EPI_NONE && EPI != EPI_QKV) v += bias[cn];
            if (EPI == EPI_GELU) v = gelu_exact(v);
            if (EPI == EPI_PROJ) v += add1[off] + add2[off];
            if (EPI == EPI_RES)  v += add1[off];
            if (EPI == EPI_PROJ || EPI == EPI_RES) Cf[off] = v;
            else                                   Cb[off] = f2bf(v);
        }
    }
}

// ---------------------------------------------------------------------------
// One-time V transpose: qkv[b][n][512+head*32+d] -> vT[(bh*32+d)][n].
// ---------------------------------------------------------------------------
#define VTPAD 136

__global__ __launch_bounds__(256) void vtrans_kernel(const short* __restrict__ qkv,
                                                     short* __restrict__ vT) {
    __shared__ short Tl[32 * VTPAD];
    const int tid = threadIdx.x;
    const int bh = blockIdx.x, c = blockIdx.y;
    const int b = bh >> 3, head = bh & 7;
    {
        int r = tid >> 1, hv = tid & 1;
        const short* src = qkv + (size_t)b * Ndim * 768 + (size_t)(c * 128 + r) * 768
                           + 512 + head * 32 + hv * 16;
        bf16x8 v0 = *(const bf16x8*)&src[0];
        bf16x8 v1 = *(const bf16x8*)&src[8];
        #pragma unroll
        for (int i = 0; i < 8; ++i) {
            Tl[(hv * 16 + i) * VTPAD + r]     = v0[i];
            Tl[(hv * 16 + 8 + i) * VTPAD + r] = v1[i];
        }
    }
    __syncthreads();
    {
        int d = tid >> 3, j16 = (tid & 7) * 16;
        short* dst = vT + (size_t)(bh * 32 + d) * Ndim + c * 128 + j16;
        *(bf16x8*)&dst[0] = *(const bf16x8*)&Tl[d * VTPAD + j16];
        *(bf16x8*)&dst[8] = *(const bf16x8*)&Tl[d * VTPAD + j16 + 8];
    }
}

// ---------------------------------------------------------------------------
// MFMA attention, SINGLE-partition flash (maxless): each block owns one
// (b,h,qblk) and walks all 8 KV chunks; l_acc is complete in-kernel (PV with
// ones), so the epilogue writes normalized O directly -> no opart x2, no
// lpart, no combine. In-register P relayout (cvt_pk + permlane32_swap),
// T14 async staging, jt software pipeline, XCD-locality decode (8 WGs of a
// (b,h) on one XCD; 16 bh/XCD -> 2MB KV per XCD L2).
// ---------------------------------------------------------------------------
#define KVPAD 40
#define CHUNK 128

__global__ __launch_bounds__(256) void attn_mfma_kernel(const short* __restrict__ qkv,
                                                        const short* __restrict__ vT,
                                                        short* __restrict__ oat) {
    __shared__ short Ks[CHUNK * KVPAD];
    __shared__ short Vt[32 * VTPAD];

    const int tid = threadIdx.x;
    const int w = tid >> 6;
    const int lane = tid & 63;
    const int col = lane & 31;
    const int half_id = lane >> 5;

    const int id = blockIdx.x;             // 0..1023
    const int xcd = id & 7;
    const int s_ = id >> 3;                // 0..127
    const int bh = ((s_ >> 3) << 3) | xcd; // 16 bh per XCD, 8 WGs per bh
    const int qblk = s_ & 7;

    const int b = bh >> 3, head = bh & 7;
    const int q0w = qblk * 128 + w * 32;

    const size_t qkvb = (size_t)b * Ndim * 768;

    const int sr = tid >> 1, shv = tid & 1;
    const short* ksrc = qkv + qkvb + (size_t)sr * 768 + 256 + head * 32 + shv * 16;
    const int sd = tid >> 3, sj16 = (tid & 7) * 16;
    const short* vsrc = vT + (size_t)(bh * 32 + sd) * Ndim + sj16;

    bf16x8 qf[2];
    {
        const short* qrow = qkv + qkvb + (size_t)(q0w + col) * 768 + head * 32;
        #pragma unroll
        for (int kh = 0; kh < 2; ++kh)
            qf[kh] = *(const bf16x8*)&qrow[kh * 16 + half_id * 8];
    }

    bf16x8 vone;
    #pragma unroll
    for (int i = 0; i < 8; ++i) vone[i] = (short)0x3F80;   // bf16 1.0

    f32x16 o_acc = 0.0f, l_acc = 0.0f;

    bf16x8 rk0, rk1, rv0, rv1;
    {
        rk0 = *(const bf16x8*)&ksrc[0];
        rk1 = *(const bf16x8*)&ksrc[8];
        rv0 = *(const bf16x8*)&vsrc[0];
        rv1 = *(const bf16x8*)&vsrc[8];
    }

    for (int ci = 0; ci < 8; ++ci) {
        if (ci != 0) __syncthreads();
        *(bf16x8*)&Ks[sr * KVPAD + shv * 16]     = rk0;
        *(bf16x8*)&Ks[sr * KVPAD + shv * 16 + 8] = rk1;
        *(bf16x8*)&Vt[sd * VTPAD + sj16]     = rv0;
        *(bf16x8*)&Vt[sd * VTPAD + sj16 + 8] = rv1;
        __syncthreads();

        // T14: issue next chunk's loads now; they land during the jt loop
        if (ci < 7) {
            const short* kp = ksrc + (size_t)((ci + 1) * CHUNK) * 768;
            rk0 = *(const bf16x8*)&kp[0];
            rk1 = *(const bf16x8*)&kp[8];
            const short* vp = vsrc + (ci + 1) * CHUNK;
            rv0 = *(const bf16x8*)&vp[0];
            rv1 = *(const bf16x8*)&vp[8];
        }

        // jt pipeline: s_cur holds QK^T(jt); QK^T(jt+1) issued before softmax(jt)
        f32x16 s_cur;
        {
            bf16x8 kf0 = *(bf16x8*)&Ks[col * KVPAD + half_id * 8];
            bf16x8 kf1 = *(bf16x8*)&Ks[col * KVPAD + 16 + half_id * 8];
            f32x16 z = 0.0f;
            z = __builtin_amdgcn_mfma_f32_32x32x16_bf16(kf0, qf[0], z, 0, 0, 0);
            z = __builtin_amdgcn_mfma_f32_32x32x16_bf16(kf1, qf[1], z, 0, 0, 0);
            s_cur = z;
        }
        #pragma unroll
        for (int jt = 0; jt < 4; ++jt) {
            f32x16 s_next;
            if (jt < 3) {
                bf16x8 kf0 = *(bf16x8*)&Ks[((jt + 1) * 32 + col) * KVPAD + half_id * 8];
                bf16x8 kf1 = *(bf16x8*)&Ks[((jt + 1) * 32 + col) * KVPAD + 16 + half_id * 8];
                f32x16 z = 0.0f;
                z = __builtin_amdgcn_mfma_f32_32x32x16_bf16(kf0, qf[0], z, 0, 0, 0);
                z = __builtin_amdgcn_mfma_f32_32x32x16_bf16(kf1, qf[1], z, 0, 0, 0);
                s_next = z;
            }

            bf16x8 vf0 = *(bf16x8*)&Vt[col * VTPAD + jt * 32 + half_id * 8];
            bf16x8 vf1 = *(bf16x8*)&Vt[col * VTPAD + jt * 32 + 16 + half_id * 8];

            u32 wd[8];
            #pragma unroll
            for (int g = 0; g < 8; ++g) {
                float e0 = fexp2(s_cur[2 * g + 0]);
                float e1 = fexp2(s_cur[2 * g + 1]);
                wd[g] = pack2bf(e0, e1);
            }
            plswap(wd[0], wd[2]); plswap(wd[1], wd[3]);
            plswap(wd[4], wd[6]); plswap(wd[5], wd[7]);

            union { u32 u[4]; bf16x8 v; } p0, p1;
            p0.u[0] = wd[0]; p0.u[1] = wd[1]; p0.u[2] = wd[2]; p0.u[3] = wd[3];
            p1.u[0] = wd[4]; p1.u[1] = wd[5]; p1.u[2] = wd[6]; p1.u[3] = wd[7];

            __builtin_amdgcn_s_setprio(1);
            o_acc = __builtin_amdgcn_mfma_f32_32x32x16_bf16(p0.v, vf0, o_acc, 0, 0, 0);
            o_acc = __builtin_amdgcn_mfma_f32_32x32x16_bf16(p1.v, vf1, o_acc, 0, 0, 0);
            l_acc = __builtin_amdgcn_mfma_f32_32x32x16_bf16(p0.v, vone, l_acc, 0, 0, 0);
            l_acc = __builtin_amdgcn_mfma_f32_32x32x16_bf16(p1.v, vone, l_acc, 0, 0, 0);
            __builtin_amdgcn_s_setprio(0);

            if (jt < 3) s_cur = s_next;
        }
    }

    // epilogue: l_acc[r] holds the complete row denominator in every column
    // (PV with all-ones B), so each lane normalizes locally.
    #pragma unroll
    for (int r = 0; r < 16; ++r) {
        int q_r = (r & 3) + 8 * (r >> 2) + 4 * half_id;
        size_t gq = (size_t)(b * Ndim + q0w + q_r);
        oat[gq * INdim + head * 32 + col] = f2bf(o_acc[r] / l_acc[r]);
    }
}

// ---------------------------------------------------------------------------
// launch
// ---------------------------------------------------------------------------
extern "C" void kernel_launch(void* const* d_in, const int* in_sizes, int n_in,
                              void* d_out, int out_size, void* d_ws, size_t ws_size,
                              hipStream_t stream) {
    const float* x     = (const float*)d_in[0];
    const float* g1    = (const float*)d_in[2];
    const float* b1    = (const float*)d_in[3];
    const float* Wqkv  = (const float*)d_in[4];
    const float* Wproj = (const float*)d_in[5];
    const float* bproj = (const float*)d_in[6];
    const float* g2    = (const float*)d_in[7];
    const float* b2    = (const float*)d_in[8];
    const float* W1    = (const float*)d_in[9];
    const float* bb1   = (const float*)d_in[10];
    const float* W2    = (const float*)d_in[11];
    const float* bb2   = (const float*)d_in[12];
    float* out = (float*)d_out;

    // workspace:
    //  [0,16M)  h fp32
    //  [16,24M) h_bf
    //  [24,48M) qkv_bf (dead after attn) -> xnew fp32 [24,40M)
    //  [48,56M) oat bf16 (normalized attention output)
    //  [56,88M) mid_bf (written after PROJ; overlaps dead vT region)
    //  [81,89M) vT bf16 (dead after attn)
    //  [89,91M) weights bf16
    char* ws = (char*)d_ws;
    float* h      = (float*)(ws);
    short* h_bf   = (short*)(ws + (size_t)(16u << 20));
    short* qkv_bf = (short*)(ws + (size_t)(24u << 20));
    float* xnew   = (float*)(ws + (size_t)(24u << 20));
    short* oat_bf = (short*)(ws + (size_t)(48u << 20));
    short* mid_bf = (short*)(ws + (size_t)(56u << 20));
    short* vT     = (short*)(ws + (size_t)(81u << 20));
    short* wqkv_b = (short*)(ws + (size_t)(89u << 20));
    short* wproj_b= (short*)(ws + (size_t)(89u << 20) + 768 * 1024);
    short* w1_b   = (short*)(ws + (size_t)(90u << 20));
    short* w2_b   = (short*)(ws + (size_t)(90u << 20) + 512 * 1024);

    // 0+1) weights -> bf16 AND LN1 in one dispatch
    cvt_ln1_kernel<<<NCVT_BLK + Tdim / 4, 256, 0, stream>>>(
        Wqkv, Wproj, W1, W2, wqkv_b, wproj_b, w1_b, w2_b,
        x, g1, b1, h, h_bf);
    // 2) qkv_bf = h_bf @ Wqkv^T (pipelined gl16 template, counted vmcnt)
    gemm128p<EPI_QKV><<<dim3(768 / 128, Tdim / 128), 256, 0, stream>>>(
        h_bf, wqkv_b, qkv_bf, 768, 256, nullptr);
    // 2b) V transpose (once)
    vtrans_kernel<<<dim3(Bdim * Hdim, Ndim / 128), 256, 0, stream>>>(qkv_bf, vT);
    // 3) attention (single partition, normalized in-kernel)
    attn_mfma_kernel<<<1024, 256, 0, stream>>>(qkv_bf, vT, oat_bf);
    // 4) xnew = oat @ Wproj^T + bproj + h + x
    gemm_mfma<EPI_PROJ, 64><<<dim3(256 / 64, Tdim / 64), 256, 0, stream>>>(
        oat_bf, wproj_b, xnew, Tdim, 256, 256, bproj, h, x);
    // 5) LN2: xnew -> h_bf
    ln4_kernel<<<Tdim / 4, 256, 0, stream>>>(xnew, g2, b2, nullptr, h_bf);
    // 6) mid_bf = gelu(h2 @ W1^T + bb1)   (pipelined template)
    gemm128p<EPI_GELU><<<dim3(1024 / 128, Tdim / 128), 256, 0, stream>>>(
        h_bf, w1_b, mid_bf, 1024, 256, bb1);
    // 7) out = xnew + mid @ W2^T + bb2   (reg-staged, R9 config)
    gemm_mfma<EPI_RES, 64><<<dim3(256 / 64, Tdim / 64), 256, 0, stream>>>(
        mid_bf, w2_b, out, Tdim, 256, 1024, bb2, xnew, nullptr);
}

// Round 15
// 205.440 us; speedup vs baseline: 1.0339x; 1.0125x over previous
//
#include <hip/hip_runtime.h>
#include <hip/hip_bf16.h>
#include <math.h>

// Shapes (fixed by the reference)
#define Bdim 16
#define Ndim 1024
#define Ddim 256
#define Hdim 8
#define HDdim 32
#define INdim 256
#define HIDdim 1024
#define Tdim (Bdim * Ndim)   // 16384 rows

typedef __attribute__((ext_vector_type(8)))  short bf16x8;
typedef __attribute__((ext_vector_type(4)))  short bf16x4;
typedef __attribute__((ext_vector_type(16))) float f32x16;
typedef unsigned int u32;

__device__ inline short f2bf(float x) {
    union { __hip_bfloat16 b; short s; } u;
    u.b = __float2bfloat16(x);
    return u.s;
}

__device__ inline float bf2f(short s) {
    return __uint_as_float(((u32)(unsigned short)s) << 16);
}

// raw v_exp_f32 (scores are bounded; no libm range handling needed)
__device__ inline float fexp2(float x) {
#if __has_builtin(__builtin_amdgcn_exp2f)
    return __builtin_amdgcn_exp2f(x);
#else
    return exp2f(x);
#endif
}

// pack two f32 -> two bf16 in a u32
__device__ inline u32 pack2bf(float a, float b) {
#if __has_builtin(__builtin_amdgcn_cvt_pk_bf16_f32)
    typedef __attribute__((ext_vector_type(2))) __bf16 bf16x2_t;
    union { bf16x2_t v; u32 u; } c;
    c.v = __builtin_amdgcn_cvt_pk_bf16_f32(a, b);
    return c.u;
#else
    u32 ua = __float_as_uint(a), ub = __float_as_uint(b);
    return ((ua + 0x8000u) >> 16) | ((ub + 0x8000u) & 0xffff0000u);
#endif
}

// v_permlane32_swap_b32: after execution a = {a.lo32, b.lo32}, b = {a.hi32, b.hi32}
__device__ inline void plswap(u32 &a, u32 &b) {
    asm volatile("v_permlane32_swap_b32 %0, %1" : "+v"(a), "+v"(b));
}

__device__ inline float gelu_exact(float v) {
    return 0.5f * v * (1.0f + erff(v * 0.70710678118654752f));
}

// direct global->LDS copy, 16B per lane. LDS dest is wave-uniform base +
// lane*16 (HW-enforced); global src is per-lane.
typedef __attribute__((address_space(1))) const u32 gas_t;
typedef __attribute__((address_space(3))) u32 las_t;
__device__ inline void gl16(const short* g, short* l) {
    __builtin_amdgcn_global_load_lds((gas_t*)g, (las_t*)l, 16, 0, 0);
}

// ---------------------------------------------------------------------------
// Fused: all four weights -> bf16 AND LN1 in ONE dispatch (blockIdx split).
// ---------------------------------------------------------------------------
#define N4_QKV  (3 * INdim * Ddim / 4)   // 49152
#define N4_PROJ (INdim * INdim / 4)      // 16384
#define N4_W1   (HIDdim * Ddim / 4)      // 65536
#define N4_W2   (Ddim * HIDdim / 4)      // 65536
#define NCVT_BLK ((N4_QKV + N4_PROJ + N4_W1 + N4_W2) / 256)   // 768

__global__ __launch_bounds__(256) void cvt_ln1_kernel(const float* __restrict__ s0,
                                                      const float* __restrict__ s1,
                                                      const float* __restrict__ s2,
                                                      const float* __restrict__ s3,
                                                      short* __restrict__ d0,
                                                      short* __restrict__ d1,
                                                      short* __restrict__ d2,
                                                      short* __restrict__ d3,
                                                      const float* __restrict__ x,
                                                      const float* __restrict__ g,
                                                      const float* __restrict__ b,
                                                      float* __restrict__ outf,
                                                      short* __restrict__ outb) {
    const int bid = blockIdx.x;
    if (bid < NCVT_BLK) {
        int i = bid * 256 + threadIdx.x;
        const float* src; short* dst; int j;
        if (i < N4_QKV)                          { src = s0; dst = d0; j = i; }
        else if (i < N4_QKV + N4_PROJ)           { src = s1; dst = d1; j = i - N4_QKV; }
        else if (i < N4_QKV + N4_PROJ + N4_W1)   { src = s2; dst = d2; j = i - N4_QKV - N4_PROJ; }
        else                                     { src = s3; dst = d3; j = i - N4_QKV - N4_PROJ - N4_W1; }
        float4 v = ((const float4*)src)[j];
        bf16x4 bb;
        bb[0] = f2bf(v.x); bb[1] = f2bf(v.y); bb[2] = f2bf(v.z); bb[3] = f2bf(v.w);
        ((bf16x4*)dst)[j] = bb;
    } else {
        int w = threadIdx.x >> 6, lane = threadIdx.x & 63;
        int row = (bid - NCVT_BLK) * 4 + w;
        float4 v = ((const float4*)x)[(size_t)row * 64 + lane];
        float s  = (v.x + v.y) + (v.z + v.w);
        float s2 = (v.x * v.x + v.y * v.y) + (v.z * v.z + v.w * v.w);
        #pragma unroll
        for (int off = 32; off; off >>= 1) {
            s  += __shfl_xor(s,  off, 64);
            s2 += __shfl_xor(s2, off, 64);
        }
        float mu   = s * (1.0f / Ddim);
        float var  = s2 * (1.0f / Ddim) - mu * mu;
        float rstd = rsqrtf(var + 1e-5f);
        float4 gg = ((const float4*)g)[lane];
        float4 bb = ((const float4*)b)[lane];
        float4 r;
        r.x = (v.x - mu) * rstd * gg.x + bb.x;
        r.y = (v.y - mu) * rstd * gg.y + bb.y;
        r.z = (v.z - mu) * rstd * gg.z + bb.z;
        r.w = (v.w - mu) * rstd * gg.w + bb.w;
        if (outf) ((float4*)outf)[(size_t)row * 64 + lane] = r;
        bf16x4 rb;
        rb[0] = f2bf(r.x); rb[1] = f2bf(r.y); rb[2] = f2bf(r.z); rb[3] = f2bf(r.w);
        ((bf16x4*)outb)[(size_t)row * 64 + lane] = rb;
    }
}

// ---------------------------------------------------------------------------
// LayerNorm, wave-per-row (4 rows/block), float4 vectorized.  (LN2)
// ---------------------------------------------------------------------------
__global__ __launch_bounds__(256) void ln4_kernel(const float* __restrict__ x,
                                                  const float* __restrict__ g,
                                                  const float* __restrict__ b,
                                                  float* __restrict__ outf,
                                                  short* __restrict__ outb) {
    int w = threadIdx.x >> 6, lane = threadIdx.x & 63;
    int row = blockIdx.x * 4 + w;
    float4 v = ((const float4*)x)[(size_t)row * 64 + lane];
    float s  = (v.x + v.y) + (v.z + v.w);
    float s2 = (v.x * v.x + v.y * v.y) + (v.z * v.z + v.w * v.w);
    #pragma unroll
    for (int off = 32; off; off >>= 1) {
        s  += __shfl_xor(s,  off, 64);
        s2 += __shfl_xor(s2, off, 64);
    }
    float mu   = s * (1.0f / Ddim);
    float var  = s2 * (1.0f / Ddim) - mu * mu;
    float rstd = rsqrtf(var + 1e-5f);
    float4 gg = ((const float4*)g)[lane];
    float4 bb = ((const float4*)b)[lane];
    float4 r;
    r.x = (v.x - mu) * rstd * gg.x + bb.x;
    r.y = (v.y - mu) * rstd * gg.y + bb.y;
    r.z = (v.z - mu) * rstd * gg.z + bb.z;
    r.w = (v.w - mu) * rstd * gg.w + bb.w;
    if (outf) ((float4*)outf)[(size_t)row * 64 + lane] = r;
    bf16x4 rb;
    rb[0] = f2bf(r.x); rb[1] = f2bf(r.y); rb[2] = f2bf(r.z); rb[3] = f2bf(r.w);
    ((bf16x4*)outb)[(size_t)row * 64 + lane] = rb;
}

// ---------------------------------------------------------------------------
// Pipelined m97 GEMM: 128x128 tile, BK=64, gl16 staging, double-buffered LDS,
// counted-vmcnt waits. Read-chunk XOR swizzle c^(row&7), inverse-swizzled src.
// EPI_QKV:  bf16 out, q-cols pre-scaled         (N=512, K=256)
// EPI_VT:   bf16 out, batched via blockIdx.z:   vT[b] = Wv @ h_b^T
// EPI_GELU: bf16 out, gelu(v + bias)            (N=1024, K=256)
// EPI_RES:  f32 out,  v + bias + add1 (xnew)    (N=256, K=1024 -> T=16,
//           the deep-K regime where the counted-vmcnt pipeline pays)
// ---------------------------------------------------------------------------
#define EPI_NONE 0
#define EPI_PROJ 1
#define EPI_GELU 2
#define EPI_RES  3
#define EPI_QKV  4
#define EPI_VT   5

#define SCALE2Q 0.25505654249892417f   // 32^-0.5 * log2(e)

template <int EPI>
__global__ __launch_bounds__(256) void gemm128p(const short* __restrict__ A,
                                                const short* __restrict__ Wp,
                                                void* __restrict__ Cv,
                                                int N, int K,
                                                const float* __restrict__ bias,
                                                const float* __restrict__ add1) {
    __shared__ __attribute__((aligned(16))) short As[2][128 * 64];
    __shared__ __attribute__((aligned(16))) short Bs[2][128 * 64];
    const int tid = threadIdx.x, w = tid >> 6, lane = tid & 63;
    const int col = lane & 31;
    const int half_id = lane >> 5;

    const short* W = Wp;
    short* Cb = (short*)Cv;
    float* Cf = (float*)Cv;
    if constexpr (EPI == EPI_VT) {
        // batch z: W = h rows of batch z; C = vT slice of batch z
        W  += (size_t)blockIdx.z * Ndim * Ddim;
        Cb += (size_t)blockIdx.z * 256 * Ndim;
    }

    // bijective XCD swizzle (per-z-slice grid size is a multiple of 8)
    const int nbx = gridDim.x;
    const int flat = blockIdx.y * nbx + blockIdx.x;
    const int cpx = (nbx * (int)gridDim.y) >> 3;
    const int swz = (flat & 7) * cpx + (flat >> 3);
    const int m0 = (swz / nbx) * 128, n0 = (swz % nbx) * 128;

    // wave tiling: 2x2 waves, each owns 64x64 (2x2 of 32x32)
    const int wm = (w & 1) * 64;
    const int wn = (w >> 1) * 64;

    f32x16 acc[2][2];
    #pragma unroll
    for (int i = 0; i < 2; ++i) { acc[i][0] = 0.0f; acc[i][1] = 0.0f; }

    const int lrow = lane >> 3;
    const int lchk = (lane & 7) ^ lrow;   // inverse of read swizzle
    const short* gA = &A[(size_t)(m0 + w * 32 + lrow) * K + lchk * 8];
    const short* gB = &W[(size_t)(n0 + w * 32 + lrow) * K + lchk * 8];

    const int T = K >> 6;   // 4 (K=256) or 16 (K=1024)

    auto STAGE = [&](int buf, int kt) {
        short* lA = &As[buf][(w * 32) * 64];
        short* lB = &Bs[buf][(w * 32) * 64];
        #pragma unroll
        for (int i = 0; i < 4; ++i) {
            gl16(gA + (size_t)(i * 8) * K + kt * 64, lA + i * 512);
            gl16(gB + (size_t)(i * 8) * K + kt * 64, lB + i * 512);
        }
    };

    STAGE(0, 0);
    if (T > 1) {
        STAGE(1, 1);
        asm volatile("s_waitcnt vmcnt(8)" ::: "memory");
    } else {
        asm volatile("s_waitcnt vmcnt(0)" ::: "memory");
    }
    __builtin_amdgcn_s_barrier();

    for (int kt = 0; kt < T; ++kt) {
        const int buf = kt & 1;
        #pragma unroll
        for (int ks = 0; ks < 4; ++ks) {
            const int c = ks * 2 + half_id;   // global chunk 0..7
            bf16x8 af[2], bfv[2];
            #pragma unroll
            for (int t = 0; t < 2; ++t) {
                const int Ra = wm + t * 32 + col;
                af[t] = *(const bf16x8*)&As[buf][Ra * 64 + ((c ^ (Ra & 7)) * 8)];
                const int Rb = wn + t * 32 + col;
                bfv[t] = *(const bf16x8*)&Bs[buf][Rb * 64 + ((c ^ (Rb & 7)) * 8)];
            }
            #pragma unroll
            for (int tm = 0; tm < 2; ++tm)
                #pragma unroll
                for (int tn = 0; tn < 2; ++tn)
                    acc[tm][tn] = __builtin_amdgcn_mfma_f32_32x32x16_bf16(
                        af[tm], bfv[tn], acc[tm][tn], 0, 0, 0);
        }
        asm volatile("s_waitcnt lgkmcnt(0)" ::: "memory");
        __builtin_amdgcn_s_barrier();
        if (kt + 2 < T) {
            STAGE(buf, kt + 2);
            asm volatile("s_waitcnt vmcnt(8)" ::: "memory");
        } else {
            asm volatile("s_waitcnt vmcnt(0)" ::: "memory");
        }
        __builtin_amdgcn_s_barrier();
    }

    #pragma unroll
    for (int tm = 0; tm < 2; ++tm) {
        #pragma unroll
        for (int r = 0; r < 16; ++r) {
            int row = m0 + wm + tm * 32 + (r & 3) + 8 * (r >> 2) + 4 * half_id;
            #pragma unroll
            for (int tn = 0; tn < 2; ++tn) {
                int cn = n0 + wn + tn * 32 + col;
                size_t off = (size_t)row * N + cn;
                float v = acc[tm][tn][r];
                if (EPI == EPI_QKV && cn < 256) v *= SCALE2Q;
                if (EPI == EPI_GELU) v = gelu_exact(v + bias[cn]);
                if (EPI == EPI_RES)  Cf[off] = v + bias[cn] + add1[off];
                else                 Cb[off] = f2bf(v);
            }
        }
    }
}

// ---------------------------------------------------------------------------
// Reg-staged GEMM, BM=64, BK=32 (R9-measured config) for PROJ.
// ---------------------------------------------------------------------------
#define GPAD32 40   // shorts per LDS row (32 data + 8 pad, 16B-aligned rows)

template <int EPI, int BN>
__global__ __launch_bounds__(256) void gemm_mfma(const short* __restrict__ A,
                                                 const short* __restrict__ W,
                                                 void* __restrict__ Cv,
                                                 int M, int N, int K,
                                                 const float* __restrict__ bias,
                                                 const float* __restrict__ add1,
                                                 const float* __restrict__ add2) {
    __shared__ short As[64 * GPAD32];
    __shared__ short Bs[BN * GPAD32];
    const int tid = threadIdx.x, w = tid >> 6, lane = tid & 63;
    const int col = lane & 31;
    const int half_id = lane >> 5;

    const int nbx = gridDim.x;
    const int flat = blockIdx.y * nbx + blockIdx.x;
    const int cpx = (nbx * (int)gridDim.y) >> 3;
    const int swz = (flat & 7) * cpx + (flat >> 3);
    const int m0 = (swz / nbx) * 64, n0 = (swz % nbx) * BN;

    const int wm = (w & 1) * 32;
    const int wn = (BN == 128) ? (w >> 1) * 64 : (w >> 1) * 32;
    constexpr int TN = (BN == 128) ? 2 : 1;

    f32x16 acc[TN];
    #pragma unroll
    for (int t = 0; t < TN; ++t) acc[t] = 0.0f;

    const int sra = tid >> 2, ssa = (tid & 3) * 8;
    const int srb = (BN == 128) ? (tid >> 1) : (tid >> 2);
    const int ssb = (BN == 128) ? (tid & 1) * 16 : (tid & 3) * 8;
    constexpr int NB = (BN == 128) ? 2 : 1;

    const short* pAsrc = &A[(size_t)(m0 + sra) * K + ssa];
    const short* pBsrc = &W[(size_t)(n0 + srb) * K + ssb];

    bf16x8 pa, pb[NB];
    pa = *(const bf16x8*)&pAsrc[0];
    #pragma unroll
    for (int j = 0; j < NB; ++j) pb[j] = *(const bf16x8*)&pBsrc[j * 8];

    const int T = K >> 5;
    for (int kt = 0; kt < T; ++kt) {
        __syncthreads();
        *(bf16x8*)&As[sra * GPAD32 + ssa] = pa;
        #pragma unroll
        for (int j = 0; j < NB; ++j) *(bf16x8*)&Bs[srb * GPAD32 + ssb + j * 8] = pb[j];
        __syncthreads();

        if (kt + 1 < T) {
            const short* a = pAsrc + (kt + 1) * 32;
            const short* b = pBsrc + (kt + 1) * 32;
            pa = *(const bf16x8*)&a[0];
            #pragma unroll
            for (int j = 0; j < NB; ++j) pb[j] = *(const bf16x8*)&b[j * 8];
        }

        #pragma unroll
        for (int ks = 0; ks < 2; ++ks) {
            bf16x8 af = *(const bf16x8*)&As[(wm + col) * GPAD32 + ks * 16 + half_id * 8];
            bf16x8 bfv[TN];
            #pragma unroll
            for (int t = 0; t < TN; ++t)
                bfv[t] = *(const bf16x8*)&Bs[(wn + t * 32 + col) * GPAD32 + ks * 16 + half_id * 8];
            #pragma unroll
            for (int t = 0; t < TN; ++t)
                acc[t] = __builtin_amdgcn_mfma_f32_32x32x16_bf16(af, bfv[t], acc[t], 0, 0, 0);
        }
    }

    float* Cf = (float*)Cv;
    short* Cb = (short*)Cv;
    #pragma unroll
    for (int r = 0; r < 16; ++r) {
        int row = m0 + wm + (r & 3) + 8 * (r >> 2) + 4 * half_id;
        #pragma unroll
        for (int t = 0; t < TN; ++t) {
            int cn = n0 + wn + t * 32 + col;
            size_t off = (size_t)row * N + cn;
            float v = acc[t][r];
            if (EPI != EPI_NONE && EPI != EPI_QKV) v += bias[cn];
            if (EPI == EPI_GELU) v = gelu_exact(v);
            if (EPI == EPI_PROJ) v += add1[off] + add2[off];
            if (EPI == EPI_RES)  v += add1[off];
            if (EPI == EPI_PROJ || EPI == EPI_RES) Cf[off] = v;
            else                                   Cb[off] = f2bf(v);
        }
    }
}

// ---------------------------------------------------------------------------
// MFMA attention, SINGLE-partition flash (maxless): each block owns one
// (b,h,qblk) and walks all 8 KV chunks; l_acc complete in-kernel (PV with
// ones) -> epilogue writes normalized O directly. In-register P relayout
// (cvt_pk + permlane32_swap), T14 async staging, jt software pipeline,
// XCD-locality decode. qk buffer holds Q|K only (stride 512); V comes from
// vT (written transposed directly by the VT-GEMM).
// ---------------------------------------------------------------------------
#define KVPAD 40
#define CHUNK 128
#define VTPAD 136

__global__ __launch_bounds__(256) void attn_mfma_kernel(const short* __restrict__ qk,
                                                        const short* __restrict__ vT,
                                                        short* __restrict__ oat) {
    __shared__ short Ks[CHUNK * KVPAD];
    __shared__ short Vt[32 * VTPAD];

    const int tid = threadIdx.x;
    const int w = tid >> 6;
    const int lane = tid & 63;
    const int col = lane & 31;
    const int half_id = lane >> 5;

    const int id = blockIdx.x;             // 0..1023
    const int xcd = id & 7;
    const int s_ = id >> 3;                // 0..127
    const int bh = ((s_ >> 3) << 3) | xcd; // 16 bh per XCD, 8 WGs per bh
    const int qblk = s_ & 7;

    const int b = bh >> 3, head = bh & 7;
    const int q0w = qblk * 128 + w * 32;

    const size_t qkb = (size_t)b * Ndim * 512;

    const int sr = tid >> 1, shv = tid & 1;
    const short* ksrc = qk + qkb + (size_t)sr * 512 + 256 + head * 32 + shv * 16;
    const int sd = tid >> 3, sj16 = (tid & 7) * 16;
    const short* vsrc = vT + (size_t)(bh * 32 + sd) * Ndim + sj16;

    bf16x8 qf[2];
    {
        const short* qrow = qk + qkb + (size_t)(q0w + col) * 512 + head * 32;
        #pragma unroll
        for (int kh = 0; kh < 2; ++kh)
            qf[kh] = *(const bf16x8*)&qrow[kh * 16 + half_id * 8];
    }

    bf16x8 vone;
    #pragma unroll
    for (int i = 0; i < 8; ++i) vone[i] = (short)0x3F80;   // bf16 1.0

    f32x16 o_acc = 0.0f, l_acc = 0.0f;

    bf16x8 rk0, rk1, rv0, rv1;
    {
        rk0 = *(const bf16x8*)&ksrc[0];
        rk1 = *(const bf16x8*)&ksrc[8];
        rv0 = *(const bf16x8*)&vsrc[0];
        rv1 = *(const bf16x8*)&vsrc[8];
    }

    for (int ci = 0; ci < 8; ++ci) {
        if (ci != 0) __syncthreads();
        *(bf16x8*)&Ks[sr * KVPAD + shv * 16]     = rk0;
        *(bf16x8*)&Ks[sr * KVPAD + shv * 16 + 8] = rk1;
        *(bf16x8*)&Vt[sd * VTPAD + sj16]     = rv0;
        *(bf16x8*)&Vt[sd * VTPAD + sj16 + 8] = rv1;
        __syncthreads();

        // T14: issue next chunk's loads now; they land during the jt loop
        if (ci < 7) {
            const short* kp = ksrc + (size_t)((ci + 1) * CHUNK) * 512;
            rk0 = *(const bf16x8*)&kp[0];
            rk1 = *(const bf16x8*)&kp[8];
            const short* vp = vsrc + (ci + 1) * CHUNK;
            rv0 = *(const bf16x8*)&vp[0];
            rv1 = *(const bf16x8*)&vp[8];
        }

        // jt pipeline: s_cur holds QK^T(jt); QK^T(jt+1) issued before softmax(jt)
        f32x16 s_cur;
        {
            bf16x8 kf0 = *(bf16x8*)&Ks[col * KVPAD + half_id * 8];
            bf16x8 kf1 = *(bf16x8*)&Ks[col * KVPAD + 16 + half_id * 8];
            f32x16 z = 0.0f;
            z = __builtin_amdgcn_mfma_f32_32x32x16_bf16(kf0, qf[0], z, 0, 0, 0);
            z = __builtin_amdgcn_mfma_f32_32x32x16_bf16(kf1, qf[1], z, 0, 0, 0);
            s_cur = z;
        }
        #pragma unroll
        for (int jt = 0; jt < 4; ++jt) {
            f32x16 s_next;
            if (jt < 3) {
                bf16x8 kf0 = *(bf16x8*)&Ks[((jt + 1) * 32 + col) * KVPAD + half_id * 8];
                bf16x8 kf1 = *(bf16x8*)&Ks[((jt + 1) * 32 + col) * KVPAD + 16 + half_id * 8];
                f32x16 z = 0.0f;
                z = __builtin_amdgcn_mfma_f32_32x32x16_bf16(kf0, qf[0], z, 0, 0, 0);
                z = __builtin_amdgcn_mfma_f32_32x32x16_bf16(kf1, qf[1], z, 0, 0, 0);
                s_next = z;
            }

            bf16x8 vf0 = *(bf16x8*)&Vt[col * VTPAD + jt * 32 + half_id * 8];
            bf16x8 vf1 = *(bf16x8*)&Vt[col * VTPAD + jt * 32 + 16 + half_id * 8];

            u32 wd[8];
            #pragma unroll
            for (int g = 0; g < 8; ++g) {
                float e0 = fexp2(s_cur[2 * g + 0]);
                float e1 = fexp2(s_cur[2 * g + 1]);
                wd[g] = pack2bf(e0, e1);
            }
            plswap(wd[0], wd[2]); plswap(wd[1], wd[3]);
            plswap(wd[4], wd[6]); plswap(wd[5], wd[7]);

            union { u32 u[4]; bf16x8 v; } p0, p1;
            p0.u[0] = wd[0]; p0.u[1] = wd[1]; p0.u[2] = wd[2]; p0.u[3] = wd[3];
            p1.u[0] = wd[4]; p1.u[1] = wd[5]; p1.u[2] = wd[6]; p1.u[3] = wd[7];

            __builtin_amdgcn_s_setprio(1);
            o_acc = __builtin_amdgcn_mfma_f32_32x32x16_bf16(p0.v, vf0, o_acc, 0, 0, 0);
            o_acc = __builtin_amdgcn_mfma_f32_32x32x16_bf16(p1.v, vf1, o_acc, 0, 0, 0);
            l_acc = __builtin_amdgcn_mfma_f32_32x32x16_bf16(p0.v, vone, l_acc, 0, 0, 0);
            l_acc = __builtin_amdgcn_mfma_f32_32x32x16_bf16(p1.v, vone, l_acc, 0, 0, 0);
            __builtin_amdgcn_s_setprio(0);

            if (jt < 3) s_cur = s_next;
        }
    }

    #pragma unroll
    for (int r = 0; r < 16; ++r) {
        int q_r = (r & 3) + 8 * (r >> 2) + 4 * half_id;
        size_t gq = (size_t)(b * Ndim + q0w + q_r);
        oat[gq * INdim + head * 32 + col] = f2bf(o_acc[r] / l_acc[r]);
    }
}

// ---------------------------------------------------------------------------
// launch
// ---------------------------------------------------------------------------
extern "C" void kernel_launch(void* const* d_in, const int* in_sizes, int n_in,
                              void* d_out, int out_size, void* d_ws, size_t ws_size,
                              hipStream_t stream) {
    const float* x     = (const float*)d_in[0];
    const float* g1    = (const float*)d_in[2];
    const float* b1    = (const float*)d_in[3];
    const float* Wqkv  = (const float*)d_in[4];
    const float* Wproj = (const float*)d_in[5];
    const float* bproj = (const float*)d_in[6];
    const float* g2    = (const float*)d_in[7];
    const float* b2    = (const float*)d_in[8];
    const float* W1    = (const float*)d_in[9];
    const float* bb1   = (const float*)d_in[10];
    const float* W2    = (const float*)d_in[11];
    const float* bb2   = (const float*)d_in[12];
    float* out = (float*)d_out;

    // workspace:
    //  [0,16M)  h fp32
    //  [16,24M) h_bf
    //  [24,40M) qk_bf (Q|K, stride 512; dead after attn) -> xnew fp32 [24,40M)
    //  [48,56M) oat bf16 (normalized attention output)
    //  [56,88M) mid_bf (written after LN2; overlaps dead vT region)
    //  [81,89M) vT bf16 (written by VT-GEMM; dead after attn)
    //  [89,91M) weights bf16
    char* ws = (char*)d_ws;
    float* h      = (float*)(ws);
    short* h_bf   = (short*)(ws + (size_t)(16u << 20));
    short* qk_bf  = (short*)(ws + (size_t)(24u << 20));
    float* xnew   = (float*)(ws + (size_t)(24u << 20));
    short* oat_bf = (short*)(ws + (size_t)(48u << 20));
    short* mid_bf = (short*)(ws + (size_t)(56u << 20));
    short* vT     = (short*)(ws + (size_t)(81u << 20));
    short* wqkv_b = (short*)(ws + (size_t)(89u << 20));
    short* wproj_b= (short*)(ws + (size_t)(89u << 20) + 768 * 1024);
    short* w1_b   = (short*)(ws + (size_t)(90u << 20));
    short* w2_b   = (short*)(ws + (size_t)(90u << 20) + 512 * 1024);
    short* wv_b   = wqkv_b + 512 * 256;   // V rows of Wqkv (contiguous)

    // 0+1) weights -> bf16 AND LN1 in one dispatch
    cvt_ln1_kernel<<<NCVT_BLK + Tdim / 4, 256, 0, stream>>>(
        Wqkv, Wproj, W1, W2, wqkv_b, wproj_b, w1_b, w2_b,
        x, g1, b1, h, h_bf);
    // 2) qk_bf = h_bf @ [Wq|Wk]^T (N=512), q cols pre-scaled
    gemm128p<EPI_QKV><<<dim3(512 / 128, Tdim / 128), 256, 0, stream>>>(
        h_bf, wqkv_b, qk_bf, 512, 256, nullptr, nullptr);
    // 2b) vT[b] = Wv @ h_b^T  (V^T computed directly; vtrans eliminated)
    gemm128p<EPI_VT><<<dim3(Ndim / 128, 256 / 128, Bdim), 256, 0, stream>>>(
        wv_b, h_bf, vT, Ndim, 256, nullptr, nullptr);
    // 3) attention (single partition, normalized in-kernel)
    attn_mfma_kernel<<<1024, 256, 0, stream>>>(qk_bf, vT, oat_bf);
    // 4) xnew = oat @ Wproj^T + bproj + h + x
    gemm_mfma<EPI_PROJ, 64><<<dim3(256 / 64, Tdim / 64), 256, 0, stream>>>(
        oat_bf, wproj_b, xnew, Tdim, 256, 256, bproj, h, x);
    // 5) LN2: xnew -> h_bf
    ln4_kernel<<<Tdim / 4, 256, 0, stream>>>(xnew, g2, b2, nullptr, h_bf);
    // 6) mid_bf = gelu(h2 @ W1^T + bb1)
    gemm128p<EPI_GELU><<<dim3(1024 / 128, Tdim / 128), 256, 0, stream>>>(
        h_bf, w1_b, mid_bf, 1024, 256, bb1, nullptr);
    // 7) out = xnew + mid @ W2^T + bb2   (K=1024 -> T=16 deep pipeline)
    gemm128p<EPI_RES><<<dim3(256 / 128, Tdim / 128), 256, 0, stream>>>(
        mid_bf, w2_b, out, 256, 1024, bb2, xnew);
}